// Round 5
// baseline (181.034 us; speedup 1.0000x reference)
//
#include <hip/hip_runtime.h>

#define EPS 1e-4f
#define NAXIS 8
#define NKNOTS 16      // interior knots; 18 total x-positions, 17 segments
#define NSEG 17
// per-batch workspace layout (floats), stride 384:
//  [0..24)    pinv[a*3+c]
//  [24..48)   uA[a*3+c]  = A[c][a] * invdx[a]   (projection straight into u-space)
//  [48..56)   uoff[a]    = -mins[a] * invdx[a]
//  [56..64)   pad
//  [64..336)  seg[a*17+s] as float2 {dy, icept}: est = dy*u + icept
#define WS_STRIDE 384
#define PXT 8                    // floats per thread per stream (2 x fv4)
#define PXB (256 * PXT)          // 2048 floats per block per stream

typedef float fv4 __attribute__((ext_vector_type(4)));   // native vector for nontemporal builtins

__global__ void spline_prep(const float* __restrict__ ys,
                            const float* __restrict__ A,
                            float* __restrict__ ws) {
    const int b = blockIdx.x;
    const float* Ab  = A  + (size_t)b * 3 * NAXIS;     // A[c*8+a]
    const float* ysb = ys + (size_t)b * NAXIS * NKNOTS;
    float* w = ws + (size_t)b * WS_STRIDE;
    __shared__ double Ginv[9];
    const int tid = threadIdx.x;

    if (tid == 0) {
        // G = A A^T (3x3, symmetric), fp64 for safety
        double G[9];
        for (int i = 0; i < 3; ++i)
            for (int j = 0; j < 3; ++j) {
                double s = 0.0;
                for (int a = 0; a < NAXIS; ++a)
                    s += (double)Ab[i * NAXIS + a] * (double)Ab[j * NAXIS + a];
                G[i * 3 + j] = s;
            }
        const double g00 = G[0], g01 = G[1], g02 = G[2];
        const double g11 = G[4], g12 = G[5], g22 = G[8];
        const double det = g00 * (g11 * g22 - g12 * g12)
                         - g01 * (g01 * g22 - g12 * g02)
                         + g02 * (g01 * g12 - g11 * g02);
        const double inv = 1.0 / det;
        Ginv[0] = (g11 * g22 - g12 * g12) * inv;
        Ginv[1] = (g02 * g12 - g01 * g22) * inv;
        Ginv[2] = (g01 * g12 - g02 * g11) * inv;
        Ginv[3] = Ginv[1];
        Ginv[4] = (g00 * g22 - g02 * g02) * inv;
        Ginv[5] = (g02 * g01 - g00 * g12) * inv;
        Ginv[6] = Ginv[2];
        Ginv[7] = Ginv[5];
        Ginv[8] = (g00 * g11 - g01 * g01) * inv;
    }
    __syncthreads();

    if (tid < 24) {                 // pinv[a][c] = sum_i A[i][a] * Ginv[i][c]
        const int a = tid / 3, c = tid % 3;
        double s = 0.0;
        for (int i = 0; i < 3; ++i)
            s += (double)Ab[i * NAXIS + a] * Ginv[i * 3 + c];
        w[a * 3 + c] = (float)s;
        float mn = 0.f, mx = 0.f;
        for (int i = 0; i < 3; ++i) {
            const float v = Ab[i * NAXIS + a];
            mn += fminf(v, 0.f);
            mx += fmaxf(v, 0.f);
        }
        const float invdx = 17.0f / (mx + EPS - mn);
        w[24 + a * 3 + c] = Ab[c * NAXIS + a] * invdx;   // uA
    }
    if (tid < NAXIS) {
        const int a = tid;
        float mn = 0.f, mx = 0.f;
        for (int c = 0; c < 3; ++c) {
            const float v = Ab[c * NAXIS + a];
            mn += fminf(v, 0.f);
            mx += fmaxf(v, 0.f);
        }
        const float range = mx + EPS - mn;
        const float invdx = 17.0f / range;
        w[48 + a] = -mn * invdx;                         // uoff
        float yf[NKNOTS + 2];
        yf[0] = mn;
        for (int k = 0; k < NKNOTS; ++k) yf[k + 1] = ysb[a * NKNOTS + k];
        yf[NKNOTS + 1] = mx;
        for (int s = 0; s < NSEG; ++s) {
            const float dy = yf[s + 1] - yf[s];
            // est(u) = dy*u + (yf[s+1] - (s+1)*dy)
            w[64 + (a * NSEG + s) * 2 + 0] = dy;
            w[64 + (a * NSEG + s) * 2 + 1] = yf[s + 1] - (float)(s + 1) * dy;
        }
    }
}

__device__ __forceinline__ float rfl(float x) {
    return __int_as_float(__builtin_amdgcn_readfirstlane(__float_as_int(x)));
}

__global__ __launch_bounds__(256) void spline_main(const float* __restrict__ raw,
                                                   const float* __restrict__ ws,
                                                   float* __restrict__ out,
                                                   int tilesPerBatch, int HW) {
    // Bijective XCD swizzle: bid%8 is the XCD; give each XCD one contiguous
    // slice of the grid (with grid = 8*tilesPerBatch this is one full batch,
    // so each XCD's 6 streams stay inside a private 24 MB region).
    int gid = blockIdx.x;
    if ((gridDim.x & 7) == 0) {
        const int q = gridDim.x >> 3;
        gid = (gid & 7) * q + (gid >> 3);
    }
    const int b    = gid / tilesPerBatch;
    const int tile = gid - b * tilesPerBatch;

    const float* w = ws + (size_t)b * WS_STRIDE;

    // 8 floats/thread/stream: 2 KB contiguous burst per wave per stream
    const size_t base = (size_t)b * 3 * HW + (size_t)tile * PXB + threadIdx.x * PXT;
    const fv4 rA = __builtin_nontemporal_load((const fv4*)(raw + base));
    const fv4 rB = __builtin_nontemporal_load((const fv4*)(raw + base + 4));
    const fv4 gA = __builtin_nontemporal_load((const fv4*)(raw + base + HW));
    const fv4 gB = __builtin_nontemporal_load((const fv4*)(raw + base + HW + 4));
    const fv4 bA = __builtin_nontemporal_load((const fv4*)(raw + base + 2 * (size_t)HW));
    const fv4 bB = __builtin_nontemporal_load((const fv4*)(raw + base + 2 * (size_t)HW + 4));

    // wave-uniform per-batch coefficients -> SGPRs via readfirstlane (cached loads)
    float cc[56];
    #pragma unroll
    for (int i = 0; i < 14; ++i) {
        const fv4 t = *(const fv4*)(w + 4 * i);
        cc[4 * i + 0] = rfl(t.x);
        cc[4 * i + 1] = rfl(t.y);
        cc[4 * i + 2] = rfl(t.z);
        cc[4 * i + 3] = rfl(t.w);
    }
    const float* cP = cc;        // pinv[a*3+c]
    const float* cA = cc + 24;   // uA[a*3+c]
    const float* cO = cc + 48;   // uoff[a]

    // only the per-lane-indexed segment table lives in LDS
    __shared__ float2 sseg[NAXIS * NSEG];
    {
        const float2* wseg = (const float2*)(w + 64);
        for (int i = threadIdx.x; i < NAXIS * NSEG; i += 256)
            sseg[i] = wseg[i];
    }
    __syncthreads();

    fv4 oA0, oA1, oA2, oB0, oB1, oB2;

    #pragma unroll
    for (int h = 0; h < 2; ++h) {
        const fv4 rr = h ? rB : rA;
        const fv4 gg = h ? gB : gA;
        const fv4 bb = h ? bB : bA;
        fv4 o0, o1, o2;
        #pragma unroll
        for (int p = 0; p < 4; ++p) {
            const float rc = rr[p], gc = gg[p], bc = bb[p];
            float a0 = 0.f, a1 = 0.f, a2 = 0.f;
            #pragma unroll
            for (int a = 0; a < NAXIS; ++a) {
                const float u = fmaf(rc, cA[a * 3 + 0],
                                 fmaf(gc, cA[a * 3 + 1],
                                 fmaf(bc, cA[a * 3 + 2], cO[a])));
                const int idx = (int)fminf(fmaxf(u, 0.f), 16.0f);   // v_med3 + cvt
                const float2 ci = sseg[a * NSEG + idx];
                const float est = fmaf(ci.x, u, ci.y);
                a0 = fmaf(est, cP[a * 3 + 0], a0);
                a1 = fmaf(est, cP[a * 3 + 1], a1);
                a2 = fmaf(est, cP[a * 3 + 2], a2);
            }
            o0[p] = a0; o1[p] = a1; o2[p] = a2;
        }
        if (h) { oB0 = o0; oB1 = o1; oB2 = o2; }
        else   { oA0 = o0; oA1 = o1; oA2 = o2; }
    }

    __builtin_nontemporal_store(oA0, (fv4*)(out + base));
    __builtin_nontemporal_store(oB0, (fv4*)(out + base + 4));
    __builtin_nontemporal_store(oA1, (fv4*)(out + base + HW));
    __builtin_nontemporal_store(oB1, (fv4*)(out + base + HW + 4));
    __builtin_nontemporal_store(oA2, (fv4*)(out + base + 2 * (size_t)HW));
    __builtin_nontemporal_store(oB2, (fv4*)(out + base + 2 * (size_t)HW + 4));
}

extern "C" void kernel_launch(void* const* d_in, const int* in_sizes, int n_in,
                              void* d_out, int out_size, void* d_ws, size_t ws_size,
                              hipStream_t stream) {
    const float* raw = (const float*)d_in[0];
    const float* ys  = (const float*)d_in[1];
    const float* A   = (const float*)d_in[2];
    float* out = (float*)d_out;
    float* ws  = (float*)d_ws;

    const int B  = in_sizes[2] / (3 * NAXIS);        // 8
    const int HW = in_sizes[0] / (B * 3);            // 1024*1024
    const int tilesPerBatch = HW / PXB;              // 512

    spline_prep<<<B, 64, 0, stream>>>(ys, A, ws);
    spline_main<<<B * tilesPerBatch, 256, 0, stream>>>(raw, ws, out, tilesPerBatch, HW);
}

// Round 6
// 178.977 us; speedup vs baseline: 1.0115x; 1.0115x over previous
//
#include <hip/hip_runtime.h>

#define EPS 1e-4f
#define NAXIS 8
#define NKNOTS 16      // interior knots; 18 total x-positions, 17 segments
#define NSEG 17
// per-batch workspace layout (floats), stride 384:
//  [0..24)    pinv[a*3+c]
//  [24..48)   uA[a*3+c]  = A[c][a] * invdx[a]
//  [48..56)   uoff[a]    = -mins[a] * invdx[a]
//  [56..64)   pad
//  [64..336)  seg[a*17+s] as float2 {dy, icept}: est = dy*u + icept
#define WS_STRIDE 384
#define TPX 2048                 // pixels per block-tile (per plane)
#define PLW 2048                 // plane words per tile in LDS

typedef float fv4 __attribute__((ext_vector_type(4)));

__global__ void spline_prep(const float* __restrict__ ys,
                            const float* __restrict__ A,
                            float* __restrict__ ws) {
    const int b = blockIdx.x;
    const float* Ab  = A  + (size_t)b * 3 * NAXIS;     // A[c*8+a]
    const float* ysb = ys + (size_t)b * NAXIS * NKNOTS;
    float* w = ws + (size_t)b * WS_STRIDE;
    __shared__ double Ginv[9];
    const int tid = threadIdx.x;

    if (tid == 0) {
        double G[9];
        for (int i = 0; i < 3; ++i)
            for (int j = 0; j < 3; ++j) {
                double s = 0.0;
                for (int a = 0; a < NAXIS; ++a)
                    s += (double)Ab[i * NAXIS + a] * (double)Ab[j * NAXIS + a];
                G[i * 3 + j] = s;
            }
        const double g00 = G[0], g01 = G[1], g02 = G[2];
        const double g11 = G[4], g12 = G[5], g22 = G[8];
        const double det = g00 * (g11 * g22 - g12 * g12)
                         - g01 * (g01 * g22 - g12 * g02)
                         + g02 * (g01 * g12 - g11 * g02);
        const double inv = 1.0 / det;
        Ginv[0] = (g11 * g22 - g12 * g12) * inv;
        Ginv[1] = (g02 * g12 - g01 * g22) * inv;
        Ginv[2] = (g01 * g12 - g02 * g11) * inv;
        Ginv[3] = Ginv[1];
        Ginv[4] = (g00 * g22 - g02 * g02) * inv;
        Ginv[5] = (g02 * g01 - g00 * g12) * inv;
        Ginv[6] = Ginv[2];
        Ginv[7] = Ginv[5];
        Ginv[8] = (g00 * g11 - g01 * g01) * inv;
    }
    __syncthreads();

    if (tid < 24) {                 // pinv[a][c] = sum_i A[i][a] * Ginv[i][c]
        const int a = tid / 3, c = tid % 3;
        double s = 0.0;
        for (int i = 0; i < 3; ++i)
            s += (double)Ab[i * NAXIS + a] * Ginv[i * 3 + c];
        w[a * 3 + c] = (float)s;
        float mn = 0.f, mx = 0.f;
        for (int i = 0; i < 3; ++i) {
            const float v = Ab[i * NAXIS + a];
            mn += fminf(v, 0.f);
            mx += fmaxf(v, 0.f);
        }
        const float invdx = 17.0f / (mx + EPS - mn);
        w[24 + a * 3 + c] = Ab[c * NAXIS + a] * invdx;   // uA
    }
    if (tid < NAXIS) {
        const int a = tid;
        float mn = 0.f, mx = 0.f;
        for (int c = 0; c < 3; ++c) {
            const float v = Ab[c * NAXIS + a];
            mn += fminf(v, 0.f);
            mx += fmaxf(v, 0.f);
        }
        const float range = mx + EPS - mn;
        const float invdx = 17.0f / range;
        w[48 + a] = -mn * invdx;                         // uoff
        float yf[NKNOTS + 2];
        yf[0] = mn;
        for (int k = 0; k < NKNOTS; ++k) yf[k + 1] = ysb[a * NKNOTS + k];
        yf[NKNOTS + 1] = mx;
        for (int s = 0; s < NSEG; ++s) {
            const float dy = yf[s + 1] - yf[s];
            w[64 + (a * NSEG + s) * 2 + 0] = dy;
            w[64 + (a * NSEG + s) * 2 + 1] = yf[s + 1] - (float)(s + 1) * dy;
        }
    }
}

__device__ __forceinline__ float rfl(float x) {
    return __int_as_float(__builtin_amdgcn_readfirstlane(__float_as_int(x)));
}

// Copy-shaped memory sides: each wave stages a contiguous 6 KB flat slice of
// the 3-plane tile (every instruction = 1 KB fully-coalesced single-plane run),
// compute happens in-place in LDS on thread-private words, and stores mirror
// the loads. Per-wave global pattern == the 6.3 TB/s copy microbenchmark.
__global__ __launch_bounds__(256) void spline_main(const float* __restrict__ raw,
                                                   const float* __restrict__ ws,
                                                   float* __restrict__ out,
                                                   int tilesPerBatch, int HW) {
    const int b    = blockIdx.x / tilesPerBatch;
    const int tile = blockIdx.x % tilesPerBatch;

    const float* w = ws + (size_t)b * WS_STRIDE;

    __shared__ float lds_t[3 * PLW];          // 24 KB tile, in/out share storage
    __shared__ float2 sseg[NAXIS * NSEG];     // 1.1 KB seg table

    const int wv = threadIdx.x >> 6;          // wave id 0..3
    const int ln = threadIdx.x & 63;
    const size_t pbase = (size_t)b * 3 * HW + (size_t)tile * TPX;

    // ---- stage in: wave wv owns flat words [wv*1536, wv*1536+1536) ----
    // each L is a 256-float (1 KB) run, 256-aligned so it never straddles a
    // plane boundary (PLW % 256 == 0): one contiguous single-plane burst.
    fv4 stg[6];
    #pragma unroll
    for (int L = 0; L < 6; ++L) {
        const int flat  = wv * 1536 + L * 256 + ln * 4;
        const int plane = flat >> 11;                 // /PLW
        const int off   = flat & (PLW - 1);
        stg[L] = __builtin_nontemporal_load((const fv4*)(raw + pbase + (size_t)plane * HW + off));
    }

    // wave-uniform per-batch coefficients -> SGPRs via readfirstlane (cached)
    float cc[56];
    #pragma unroll
    for (int i = 0; i < 14; ++i) {
        const fv4 t = *(const fv4*)(w + 4 * i);
        cc[4 * i + 0] = rfl(t.x);
        cc[4 * i + 1] = rfl(t.y);
        cc[4 * i + 2] = rfl(t.z);
        cc[4 * i + 3] = rfl(t.w);
    }
    const float* cP = cc;        // pinv[a*3+c]
    const float* cA = cc + 24;   // uA[a*3+c]
    const float* cO = cc + 48;   // uoff[a]

    {   // seg table (cached global loads)
        const float2* wseg = (const float2*)(w + 64);
        for (int i = threadIdx.x; i < NAXIS * NSEG; i += 256)
            sseg[i] = wseg[i];
    }

    #pragma unroll
    for (int L = 0; L < 6; ++L) {
        const int flat = wv * 1536 + L * 256 + ln * 4;
        *(fv4*)(lds_t + flat) = stg[L];       // lane stride 4 words: conflict-free b128
    }
    __syncthreads();

    // ---- compute in place: thread t owns words [t*4, t*4+4) of each plane,
    // in two halves; reads precede writes on the same thread-private words,
    // so no barrier is needed inside this phase.
    const int t4 = threadIdx.x * 4;
    #pragma unroll
    for (int h = 0; h < 2; ++h) {
        const int p0 = h * 1024 + t4;
        const fv4 rr = *(const fv4*)(lds_t + p0);
        const fv4 gg = *(const fv4*)(lds_t + PLW + p0);
        const fv4 bb = *(const fv4*)(lds_t + 2 * PLW + p0);
        fv4 o0, o1, o2;
        #pragma unroll
        for (int p = 0; p < 4; ++p) {
            const float rc = rr[p], gc = gg[p], bc = bb[p];
            float a0 = 0.f, a1 = 0.f, a2 = 0.f;
            #pragma unroll
            for (int a = 0; a < NAXIS; ++a) {
                const float u = fmaf(rc, cA[a * 3 + 0],
                                 fmaf(gc, cA[a * 3 + 1],
                                 fmaf(bc, cA[a * 3 + 2], cO[a])));
                const int idx = (int)fminf(fmaxf(u, 0.f), 16.0f);
                const float2 ci = sseg[a * NSEG + idx];
                const float est = fmaf(ci.x, u, ci.y);
                a0 = fmaf(est, cP[a * 3 + 0], a0);
                a1 = fmaf(est, cP[a * 3 + 1], a1);
                a2 = fmaf(est, cP[a * 3 + 2], a2);
            }
            o0[p] = a0; o1[p] = a1; o2[p] = a2;
        }
        *(fv4*)(lds_t + p0)           = o0;
        *(fv4*)(lds_t + PLW + p0)     = o1;
        *(fv4*)(lds_t + 2 * PLW + p0) = o2;
    }
    __syncthreads();

    // ---- stage out: mirror of the load pattern, nontemporal ----
    #pragma unroll
    for (int L = 0; L < 6; ++L) {
        const int flat  = wv * 1536 + L * 256 + ln * 4;
        const int plane = flat >> 11;
        const int off   = flat & (PLW - 1);
        const fv4 v = *(const fv4*)(lds_t + flat);
        __builtin_nontemporal_store(v, (fv4*)(out + pbase + (size_t)plane * HW + off));
    }
}

extern "C" void kernel_launch(void* const* d_in, const int* in_sizes, int n_in,
                              void* d_out, int out_size, void* d_ws, size_t ws_size,
                              hipStream_t stream) {
    const float* raw = (const float*)d_in[0];
    const float* ys  = (const float*)d_in[1];
    const float* A   = (const float*)d_in[2];
    float* out = (float*)d_out;
    float* ws  = (float*)d_ws;

    const int B  = in_sizes[2] / (3 * NAXIS);        // 8
    const int HW = in_sizes[0] / (B * 3);            // 1024*1024
    const int tilesPerBatch = HW / TPX;              // 512

    spline_prep<<<B, 64, 0, stream>>>(ys, A, ws);
    spline_main<<<B * tilesPerBatch, 256, 0, stream>>>(raw, ws, out, tilesPerBatch, HW);
}